// Round 2
// baseline (63906.720 us; speedup 1.0000x reference)
//
#include <hip/hip_runtime.h>
#include <hip/hip_bf16.h>

namespace {
constexpr int B  = 64;
constexpr int T  = 2048;
constexpr int L  = 200;
constexpr int H  = 256;
constexpr int KV = 256;
constexpr int E  = 256;
constexpr int V  = 33;
constexpr int MH = 512;
constexpr int G  = 4 * H;
constexpr int HB = H * B;

// float workspace layout (offsets in floats)
constexpr long OFF_H   = 0;                        // h double buffer [2][3][H][B]
constexpr long OFF_C   = OFF_H  + 2L * 3 * HB;     // c [3][H][B]
constexpr long OFF_CTX = OFF_C  + 3L * HB;         // ctx' double buffer [2][KV][B]
constexpr long OFF_Z   = OFF_CTX + 2L * KV * B;    // Z' [2][B]
constexpr long OFF_M   = OFF_Z  + 2L * B;          // m [B] (legacy path only)
constexpr long OFF_E   = OFF_M  + B;               // e [B][T] (legacy path only)
constexpr long OFF_HID = OFF_E  + (long)B * T;     // hiddenT [MH][B]
constexpr long OFF_XE  = OFF_HID + (long)MH * B;   // xembT [L][E][B]
constexpr long OFF_BAR = OFF_XE + (long)L * E * B; // barrier counter (+pad)
constexpr long FLOATS  = OFF_BAR + 16;
constexpr long FLOATBYTES = FLOATS * 4;
constexpr long KVELEMS = (long)B * T * KV;
constexpr long NEED_BF = FLOATBYTES + 2 * KVELEMS * 2;
}

__device__ __forceinline__ float sigm(float x) { return 1.f / (1.f + __expf(-x)); }
__device__ __forceinline__ float tanh_f(float x) {
  float xc = fminf(fmaxf(x, -15.f), 15.f);
  float e2 = __expf(2.f * xc);
  return (e2 - 1.f) / (e2 + 1.f);
}
__device__ __forceinline__ ushort f2bf(float x) {
  unsigned u = __float_as_uint(x);
  unsigned r = (u + 0x7fffu + ((u >> 16) & 1u)) >> 16;
  return (ushort)r;
}
__device__ __forceinline__ float bf2f(unsigned v) { return __uint_as_float(v << 16); }

__device__ __forceinline__ void atomicMaxFloat(float* p, float v) {
  int old = __float_as_int(*p);
  while (__int_as_float(old) < v) {
    int assumed = old;
    old = atomicCAS((int*)p, assumed, __float_as_int(v));
    if (old == assumed) break;
  }
}

// ---------- one-time kernels ----------
__global__ void k_init(float* __restrict__ ws) {
  int i = blockIdx.x * blockDim.x + threadIdx.x;
  if (i < 3 * HB) { ws[OFF_H + i] = 0.f; ws[OFF_C + i] = 0.f; }
  if (i < KV * B) ws[OFF_CTX + i] = 0.f;
  if (i < B)      ws[OFF_Z + i] = 1.f;
  if (i < 16)     ws[OFF_BAR + i] = 0.f;   // zero barrier counter (0.f == bits 0)
}

__global__ void k_embed(const int* __restrict__ labels, const float* __restrict__ emb,
                        float* __restrict__ xembT) {
  int i = blockIdx.x * blockDim.x + threadIdx.x;
  if (i >= L * E * B) return;
  int b = i & 63, e = (i >> 6) & 255, l = i >> 14;
  int lab = labels[l * B + b];
  xembT[i] = emb[lab * E + e];
}

__global__ void k_cvt(const float4* __restrict__ src, ushort4* __restrict__ dst, int n4) {
  int i = blockIdx.x * blockDim.x + threadIdx.x;
  int stride = gridDim.x * blockDim.x;
  for (int k = i; k < n4; k += stride) {
    float4 v = src[k];
    ushort4 o;
    o.x = f2bf(v.x); o.y = f2bf(v.y); o.z = f2bf(v.z); o.w = f2bf(v.w);
    dst[k] = o;
  }
}

// ================= persistent cooperative kernel =================

// monotone grid barrier: every block adds 1; wait until counter >= target.
__device__ __forceinline__ void gsync(unsigned* bar, unsigned target) {
  __syncthreads();
  if (threadIdx.x == 0) {
    __threadfence();                       // release (agent scope: wb L1/L2)
    atomicAdd(bar, 1u);
    unsigned spins = 0;
    while (__hip_atomic_load(bar, __ATOMIC_RELAXED, __HIP_MEMORY_SCOPE_AGENT) < target) {
      __builtin_amdgcn_s_sleep(1);
      if (++spins > 100000000u) break;     // safety valve: garbage > eternal hang
    }
    __threadfence();                       // acquire (invalidate stale lines)
  }
  __syncthreads();
}

// one LSTM cell output row j for all 64 batches; block = 256 thr (64 b x 4 gates)
template <int HAS2>
__device__ __forceinline__ void lstm_cell_block(
    int j, int tid,
    const float* __restrict__ wih, long wpitch,
    const float* __restrict__ whh,
    const float* __restrict__ bih, const float* __restrict__ bhh,
    const float* __restrict__ A,    // [256][64] input part 1
    const float* __restrict__ C2,   // [256][64] input part 2 (scaled by 1/Z), or null
    const float* __restrict__ Zc,   // [64], or null
    const float* __restrict__ hp,   // [256][64] recurrent
    float* __restrict__ ho, float* __restrict__ cs,
    float* smem) {
  int b = tid & 63, q = tid >> 6;
  int row = q * H + j;
  const float* wi = wih + (long)row * wpitch;
  const float* wh = whh + (long)row * H;
  float s0 = 0.f, s1 = 0.f, s2 = 0.f, s3 = 0.f;
  #pragma unroll 4
  for (int k = 0; k < 256; k += 4) {
    s0 += wi[k]   * A[(k)   * 64 + b];
    s1 += wi[k+1] * A[(k+1) * 64 + b];
    s2 += wi[k+2] * A[(k+2) * 64 + b];
    s3 += wi[k+3] * A[(k+3) * 64 + b];
  }
  float acc = bih[row] + bhh[row] + (s0 + s1) + (s2 + s3);
  if (HAS2) {
    float c0 = 0.f, c1 = 0.f, c2 = 0.f, c3 = 0.f;
    #pragma unroll 4
    for (int k = 0; k < 256; k += 4) {
      c0 += wi[256 + k]   * C2[(k)   * 64 + b];
      c1 += wi[256 + k+1] * C2[(k+1) * 64 + b];
      c2 += wi[256 + k+2] * C2[(k+2) * 64 + b];
      c3 += wi[256 + k+3] * C2[(k+3) * 64 + b];
    }
    float zz = 1.f / fmaxf(Zc[b], 1e-12f);
    acc += ((c0 + c1) + (c2 + c3)) * zz;
  }
  float h0 = 0.f, h1 = 0.f, h2 = 0.f, h3 = 0.f;
  #pragma unroll 4
  for (int k = 0; k < 256; k += 4) {
    h0 += wh[k]   * hp[(k)   * 64 + b];
    h1 += wh[k+1] * hp[(k+1) * 64 + b];
    h2 += wh[k+2] * hp[(k+2) * 64 + b];
    h3 += wh[k+3] * hp[(k+3) * 64 + b];
  }
  acc += (h0 + h1) + (h2 + h3);
  smem[q * 64 + b] = acc;
  __syncthreads();
  if (tid < 64) {
    float gi = smem[tid], gf = smem[64 + tid], gg = smem[128 + tid], go = smem[192 + tid];
    float c = sigm(gf) * cs[j * 64 + tid] + sigm(gi) * tanh_f(gg);
    float h = sigm(go) * tanh_f(c);
    cs[j * 64 + tid] = c;
    ho[j * 64 + tid] = h;
  }
  __syncthreads();
}

__global__ __launch_bounds__(256, 4) void k_persist(
    const ushort* __restrict__ kbf, const ushort* __restrict__ vbf,
    const int* __restrict__ lens,
    const float* __restrict__ w_ih0, const float* __restrict__ w_hh0,
    const float* __restrict__ b_ih0, const float* __restrict__ b_hh0,
    const float* __restrict__ w_ihr, const float* __restrict__ w_hhr,
    const float* __restrict__ b_ihr, const float* __restrict__ b_hhr,
    const float* __restrict__ fc1_w, const float* __restrict__ fc1_b,
    const float* __restrict__ fc2_w, const float* __restrict__ fc2_b,
    float* __restrict__ out, float* __restrict__ ws) {
  const int g = blockIdx.x, tid = threadIdx.x;
  const unsigned nb = gridDim.x;
  unsigned* bar = (unsigned*)(ws + OFF_BAR);
  float* hbuf = ws + OFF_H;
  float* cbuf = ws + OFF_C;
  float* ctxb = ws + OFF_CTX;
  float* Zb   = ws + OFF_Z;
  float* hid  = ws + OFF_HID;
  float* xe   = ws + OFF_XE;
  __shared__ float smem[1032];
  unsigned ep = 0;

  for (int t = 0; t <= L; ++t) {
    const int cur = t & 1, nxt = cur ^ 1;
    float* hcur = hbuf + (long)cur * 3 * HB;
    float* hn   = hbuf + (long)nxt * 3 * HB;
    float* ctxc = ctxb + (long)cur * KV * B;
    float* ctxn = ctxb + (long)nxt * KV * B;
    float* Zc = Zb + cur * B;
    float* Zn = Zb + nxt * B;

    // ---- PHASE A: cell0 | fc1(t-1) | zero ctxn/Zn ----
    if (t < L && g < 256) {
      lstm_cell_block<1>(g, tid, w_ih0, E + KV, w_hh0, b_ih0, b_hh0,
                         xe + (long)t * E * B, ctxc, Zc, hcur, hn, cbuf, smem);
    } else if (t > 0 && g >= 256 && g < 384) {
      int b = tid & 63, q = tid >> 6;
      int j = (g - 256) * 4 + q;
      const float* h2p = hcur + 2 * HB;
      const float* wr = fc1_w + (long)j * (H + KV);
      float zz = 1.f / fmaxf(Zc[b], 1e-12f);
      float s0 = 0.f, s1 = 0.f, c0 = 0.f, c1 = 0.f;
      #pragma unroll 4
      for (int k = 0; k < 256; k += 2) {
        s0 += wr[k]   * h2p[(k)   * 64 + b];
        s1 += wr[k+1] * h2p[(k+1) * 64 + b];
        c0 += wr[256 + k]   * ctxc[(k)   * 64 + b];
        c1 += wr[256 + k+1] * ctxc[(k+1) * 64 + b];
      }
      float acc = fc1_b[j] + (s0 + s1) + (c0 + c1) * zz;
      hid[j * 64 + b] = fmaxf(acc, 0.f);
    } else if (t < L && g >= 384 && g < 448) {
      ctxn[(g - 384) * 256 + tid] = 0.f;
    } else if (t < L && g == 448) {
      if (tid < B) Zn[tid] = 0.f;
    }
    ep += nb; gsync(bar, ep);

    // ---- PHASE B: cell1 | fc2(t-1) ----
    if (t < L && g < 256) {
      lstm_cell_block<0>(g, tid, w_ihr, H, w_hhr, b_ihr, b_hhr,
                         hn, nullptr, nullptr, hcur + HB, hn + HB, cbuf + HB, smem);
    } else if (t > 0 && g >= 256 && g < 256 + V) {
      int v = g - 256;
      int b = tid & 63, ks = tid >> 6;
      const float* wr = fc2_w + (long)v * MH + ks * 128;
      float s = 0.f;
      #pragma unroll 4
      for (int k = 0; k < 128; ++k) s += wr[k] * hid[(ks * 128 + k) * 64 + b];
      smem[ks * 64 + b] = s;
      __syncthreads();
      if (tid < 64) {
        float r = smem[tid] + smem[64 + tid] + smem[128 + tid] + smem[192 + tid] + fc2_b[v];
        out[((long)tid * L + (t - 1)) * V + v] = r;
      }
      __syncthreads();
    }
    ep += nb; gsync(bar, ep);
    if (t == L) break;

    // ---- PHASE C: cell2 ----
    if (g < 256) {
      lstm_cell_block<0>(g, tid, w_ihr + (long)G * H, H, w_hhr + (long)G * H,
                         b_ihr + G, b_hhr + G,
                         hn + HB, nullptr, nullptr, hcur + 2 * HB, hn + 2 * HB,
                         cbuf + 2 * HB, smem);
    }
    ep += nb; gsync(bar, ep);

    // ---- PHASE D: fused attention (no max pass; exp clamped) ----
    {
      const float* h2 = hn + 2 * HB;
      const int ntiles = B * (T / 128);
      for (int tile = g; tile < ntiles; tile += (int)nb) {
        int b = tile >> 4, chunk = tile & 15;
        int len = lens[b];
        int r0 = chunk * 128;
        if (r0 < len) {
          int wave = tid >> 6, lane = tid & 63;
          float q0 = h2[(4 * lane + 0) * 64 + b];
          float q1 = h2[(4 * lane + 1) * 64 + b];
          float q2 = h2[(4 * lane + 2) * 64 + b];
          float q3 = h2[(4 * lane + 3) * 64 + b];
          float a0 = 0.f, a1 = 0.f, a2 = 0.f, a3 = 0.f, zp = 0.f;
          int rs = r0 + wave * 32;
          int re = min(rs + 32, len);
          for (int r = rs; r < re; ++r) {
            size_t off = ((size_t)(b * T + r)) * KV + 4 * lane;
            uint2 kd = *(const uint2*)(kbf + off);
            uint2 vd = *(const uint2*)(vbf + off);
            float e = bf2f(kd.x & 0xffffu) * q0
                    + __uint_as_float(kd.x & 0xffff0000u) * q1
                    + bf2f(kd.y & 0xffffu) * q2
                    + __uint_as_float(kd.y & 0xffff0000u) * q3;
            #pragma unroll
            for (int o = 32; o; o >>= 1) e += __shfl_xor(e, o, 64);
            float w = __expf(fminf(e, 50.f));
            a0 += w * bf2f(vd.x & 0xffffu);
            a1 += w * __uint_as_float(vd.x & 0xffff0000u);
            a2 += w * bf2f(vd.y & 0xffffu);
            a3 += w * __uint_as_float(vd.y & 0xffff0000u);
            zp += w;
          }
          smem[wave * 256 + 4 * lane + 0] = a0;
          smem[wave * 256 + 4 * lane + 1] = a1;
          smem[wave * 256 + 4 * lane + 2] = a2;
          smem[wave * 256 + 4 * lane + 3] = a3;
          if (lane == 0) smem[1024 + wave] = zp;
        }
        __syncthreads();
        if (r0 < len) {
          float s = smem[tid] + smem[256 + tid] + smem[512 + tid] + smem[768 + tid];
          atomicAdd(&ctxn[tid * 64 + b], s);
          if (tid == 0)
            atomicAdd(&Zn[b], smem[1024] + smem[1025] + smem[1026] + smem[1027]);
        }
        __syncthreads();
      }
    }
    ep += nb; gsync(bar, ep);
  }
}

// ================= legacy (round-0) fallback kernels =================

__global__ __launch_bounds__(512) void k_cell0(
    const float* __restrict__ wih, const float* __restrict__ whh,
    const float* __restrict__ bih, const float* __restrict__ bhh,
    const float* __restrict__ xe,
    const float* __restrict__ ctx, const float* __restrict__ Z,
    const float* __restrict__ hprev,
    float* __restrict__ hnew, float* __restrict__ cst) {
  int t = threadIdx.x;
  int b = t & 63, q = (t >> 6) & 3, ks = t >> 8;
  int j = blockIdx.x;
  int row = q * H + j;
  float acc = 0.f, s0 = 0.f, s1 = 0.f, s2 = 0.f, s3 = 0.f, a2 = 0.f;
  if (ks == 0) {
    acc = bih[row] + bhh[row];
    const float* wi = wih + (long)row * (E + KV);
    #pragma unroll 4
    for (int k = 0; k < E; k += 4) {
      s0 += wi[k]   * xe[(k)   * B + b];
      s1 += wi[k+1] * xe[(k+1) * B + b];
      s2 += wi[k+2] * xe[(k+2) * B + b];
      s3 += wi[k+3] * xe[(k+3) * B + b];
    }
    const float* wh = whh + (long)row * H;
    #pragma unroll 4
    for (int k = 0; k < 128; k += 2) {
      a2 += wh[k]   * hprev[(k)   * B + b];
      a2 += wh[k+1] * hprev[(k+1) * B + b];
    }
    acc += (s0 + s1) + (s2 + s3) + a2;
  } else {
    float zz = 1.f / fmaxf(Z[b], 1e-12f);
    const float* wi = wih + (long)row * (E + KV) + E;
    #pragma unroll 4
    for (int k = 0; k < KV; k += 4) {
      s0 += wi[k]   * ctx[(k)   * B + b];
      s1 += wi[k+1] * ctx[(k+1) * B + b];
      s2 += wi[k+2] * ctx[(k+2) * B + b];
      s3 += wi[k+3] * ctx[(k+3) * B + b];
    }
    const float* wh = whh + (long)row * H + 128;
    #pragma unroll 4
    for (int k = 0; k < 128; k += 2) {
      a2 += wh[k]   * hprev[(128 + k)     * B + b];
      a2 += wh[k+1] * hprev[(128 + k + 1) * B + b];
    }
    acc = ((s0 + s1) + (s2 + s3)) * zz + a2;
  }
  __shared__ float sh[2][4][64];
  sh[ks][q][b] = acc;
  __syncthreads();
  if (t < 64) {
    int bb = t;
    float gi = sh[0][0][bb] + sh[1][0][bb];
    float gf = sh[0][1][bb] + sh[1][1][bb];
    float gg = sh[0][2][bb] + sh[1][2][bb];
    float go = sh[0][3][bb] + sh[1][3][bb];
    float c = sigm(gf) * cst[j * B + bb] + sigm(gi) * tanh_f(gg);
    float h = sigm(go) * tanh_f(c);
    cst[j * B + bb] = c;
    hnew[j * B + bb] = h;
  }
}

__global__ __launch_bounds__(512) void k_cellr(
    const float* __restrict__ wih, const float* __restrict__ whh,
    const float* __restrict__ bih, const float* __restrict__ bhh,
    const float* __restrict__ hin, const float* __restrict__ hprevL,
    float* __restrict__ hnewL, float* __restrict__ cst,
    float* __restrict__ ctxn, float* __restrict__ Zn, float* __restrict__ m, int aux) {
  int t = threadIdx.x;
  int b = t & 63, q = (t >> 6) & 3, ks = t >> 8;
  int j = blockIdx.x;
  int row = q * H + j;
  if (aux) {
    int gid = blockIdx.x * 512 + t;
    if (gid < KV * B) ctxn[gid] = 0.f;
    if (gid < B) { Zn[gid] = 0.f; m[gid] = -3.4e38f; }
  }
  float acc = ks ? 0.f : (bih[row] + bhh[row]);
  float a1 = 0.f, a2 = 0.f, a3 = 0.f, a4 = 0.f;
  const float* wi = wih + (long)row * H + ks * 128;
  const float* wh = whh + (long)row * H + ks * 128;
  int k0 = ks * 128;
  #pragma unroll 4
  for (int k = 0; k < 128; k += 2) {
    a1 += wi[k]   * hin[(k0 + k)     * B + b];
    a2 += wi[k+1] * hin[(k0 + k + 1) * B + b];
    a3 += wh[k]   * hprevL[(k0 + k)     * B + b];
    a4 += wh[k+1] * hprevL[(k0 + k + 1) * B + b];
  }
  acc += (a1 + a2) + (a3 + a4);
  __shared__ float sh[2][4][64];
  sh[ks][q][b] = acc;
  __syncthreads();
  if (t < 64) {
    int bb = t;
    float gi = sh[0][0][bb] + sh[1][0][bb];
    float gf = sh[0][1][bb] + sh[1][1][bb];
    float gg = sh[0][2][bb] + sh[1][2][bb];
    float go = sh[0][3][bb] + sh[1][3][bb];
    float c = sigm(gf) * cst[j * B + bb] + sigm(gi) * tanh_f(gg);
    float h = sigm(go) * tanh_f(c);
    cst[j * B + bb] = c;
    hnewL[j * B + bb] = h;
  }
}

template <int BF>
__global__ __launch_bounds__(256) void k_energy(
    const void* __restrict__ keyp, const float* __restrict__ h2,
    const int* __restrict__ lens, float* __restrict__ e, float* __restrict__ m) {
  int b = blockIdx.y;
  int len = lens[b];
  int wave = threadIdx.x >> 6, lane = threadIdx.x & 63;
  int t0 = (blockIdx.x * 4 + wave) * 16;
  if (t0 >= len) return;
  float h0 = h2[(4 * lane + 0) * B + b];
  float h1 = h2[(4 * lane + 1) * B + b];
  float h2v = h2[(4 * lane + 2) * B + b];
  float h3 = h2[(4 * lane + 3) * B + b];
  int tend = min(t0 + 16, len);
  float wmax = -3.4e38f;
  for (int t = t0; t < tend; t++) {
    float4 kv;
    if (BF) {
      const uint2* p = (const uint2*)((const ushort*)keyp + (size_t)(b * T + t) * KV + 4 * lane);
      uint2 d = *p;
      kv.x = bf2f(d.x & 0xffffu);
      kv.y = __uint_as_float(d.x & 0xffff0000u);
      kv.z = bf2f(d.y & 0xffffu);
      kv.w = __uint_as_float(d.y & 0xffff0000u);
    } else {
      kv = ((const float4*)((const float*)keyp + (size_t)(b * T + t) * KV))[lane];
    }
    float s = kv.x * h0 + kv.y * h1 + kv.z * h2v + kv.w * h3;
    #pragma unroll
    for (int off = 32; off; off >>= 1) s += __shfl_xor(s, off, 64);
    if (lane == 0) e[b * T + t] = s;
    wmax = fmaxf(wmax, s);
  }
  if (lane == 0) atomicMaxFloat(&m[b], wmax);
}

template <int BF>
__global__ __launch_bounds__(256) void k_pv(
    const void* __restrict__ valp, const float* __restrict__ e, const float* __restrict__ m,
    const int* __restrict__ lens, float* __restrict__ ctxn, float* __restrict__ Zn) {
  int b = blockIdx.y;
  int len = lens[b];
  int t0blk = blockIdx.x * 256;
  if (t0blk >= len) return;
  int wave = threadIdx.x >> 6, lane = threadIdx.x & 63;
  float mb = m[b];
  float a0 = 0.f, a1 = 0.f, a2 = 0.f, a3 = 0.f, zp = 0.f;
  int t0 = t0blk + wave * 64;
  int tend = min(t0 + 64, len);
  for (int t = t0; t < tend; t++) {
    float w = __expf(e[b * T + t] - mb);
    float4 vv;
    if (BF) {
      const uint2* p = (const uint2*)((const ushort*)valp + (size_t)(b * T + t) * KV + 4 * lane);
      uint2 d = *p;
      vv.x = bf2f(d.x & 0xffffu);
      vv.y = __uint_as_float(d.x & 0xffff0000u);
      vv.z = bf2f(d.y & 0xffffu);
      vv.w = __uint_as_float(d.y & 0xffff0000u);
    } else {
      vv = ((const float4*)((const float*)valp + (size_t)(b * T + t) * KV))[lane];
    }
    a0 += w * vv.x; a1 += w * vv.y; a2 += w * vv.z; a3 += w * vv.w;
    zp += w;
  }
  __shared__ float sh[4][256];
  __shared__ float shz[4];
  sh[wave][4 * lane + 0] = a0;
  sh[wave][4 * lane + 1] = a1;
  sh[wave][4 * lane + 2] = a2;
  sh[wave][4 * lane + 3] = a3;
  if (lane == 0) shz[wave] = zp;
  __syncthreads();
  if (wave == 0) {
    #pragma unroll
    for (int r = 0; r < 4; r++) {
      int d = lane * 4 + r;
      float s = sh[0][d] + sh[1][d] + sh[2][d] + sh[3][d];
      atomicAdd(&ctxn[d * B + b], s);
    }
    if (lane == 0) atomicAdd(&Zn[b], shz[0] + shz[1] + shz[2] + shz[3]);
  }
}

__global__ __launch_bounds__(256) void k_fc1(
    const float* __restrict__ w, const float* __restrict__ bias,
    const float* __restrict__ h2, const float* __restrict__ ctxn, const float* __restrict__ Zn,
    float* __restrict__ hid) {
  int t = threadIdx.x;
  int b = t & 63, jl = t >> 6;
  int j = blockIdx.x * 4 + jl;
  float zz = 1.f / fmaxf(Zn[b], 1e-12f);
  const float* wr = w + (long)j * (H + KV);
  float s0 = 0.f, s1 = 0.f, s2 = 0.f, s3 = 0.f, a2 = 0.f, a3 = 0.f;
  #pragma unroll 4
  for (int k = 0; k < H; k += 4) {
    s0 += wr[k]   * h2[(k)   * B + b];
    s1 += wr[k+1] * h2[(k+1) * B + b];
    s2 += wr[k+2] * h2[(k+2) * B + b];
    s3 += wr[k+3] * h2[(k+3) * B + b];
  }
  #pragma unroll 4
  for (int k = 0; k < KV; k += 2) {
    a2 += wr[H + k]     * ctxn[(k)   * B + b];
    a3 += wr[H + k + 1] * ctxn[(k+1) * B + b];
  }
  float acc = bias[j] + (s0 + s1) + (s2 + s3) + (a2 + a3) * zz;
  hid[j * B + b] = fmaxf(acc, 0.f);
}

__global__ __launch_bounds__(64) void k_fc2(
    const float* __restrict__ w, const float* __restrict__ bias,
    const float* __restrict__ hid, float* __restrict__ out, int step) {
  int b = threadIdx.x;
  int v = blockIdx.x;
  const float* wr = w + (long)v * MH;
  float s0 = 0.f, s1 = 0.f, s2 = 0.f, s3 = 0.f;
  #pragma unroll 4
  for (int k = 0; k < MH; k += 4) {
    s0 += wr[k]   * hid[(k)   * B + b];
    s1 += wr[k+1] * hid[(k+1) * B + b];
    s2 += wr[k+2] * hid[(k+2) * B + b];
    s3 += wr[k+3] * hid[(k+3) * B + b];
  }
  out[((long)b * L + step) * V + v] = bias[v] + (s0 + s1) + (s2 + s3);
}

static void launch_legacy(const float* key, const float* value, const int* lens,
                          const float* w_ih0, const float* w_hh0,
                          const float* b_ih0, const float* b_hh0,
                          const float* w_ihr, const float* w_hhr,
                          const float* b_ihr, const float* b_hhr,
                          const float* fc1_w, const float* fc1_b,
                          const float* fc2_w, const float* fc2_b,
                          float* out, float* ws,
                          const ushort* kbf, const ushort* vbf, bool bf,
                          hipStream_t stream) {
  float* hbuf = ws + OFF_H;
  float* cbuf = ws + OFF_C;
  float* ctxb = ws + OFF_CTX;
  float* Zb   = ws + OFF_Z;
  float* mb   = ws + OFF_M;
  float* eb   = ws + OFF_E;
  float* hid  = ws + OFF_HID;
  float* xe   = ws + OFF_XE;
  for (int t = 0; t < L; t++) {
    int cur = t & 1, nxt = cur ^ 1;
    float* hprev = hbuf + (long)cur * 3 * HB;
    float* hnew  = hbuf + (long)nxt * 3 * HB;
    float* ctxc  = ctxb + (long)cur * KV * B;
    float* ctxn  = ctxb + (long)nxt * KV * B;
    float* Zc = Zb + cur * B;
    float* Zn = Zb + nxt * B;

    k_cell0<<<H, 512, 0, stream>>>(w_ih0, w_hh0, b_ih0, b_hh0,
                                   xe + (long)t * E * B, ctxc, Zc,
                                   hprev, hnew, cbuf);
    k_cellr<<<H, 512, 0, stream>>>(w_ihr, w_hhr, b_ihr, b_hhr,
                                   hnew, hprev + HB, hnew + HB, cbuf + HB,
                                   ctxn, Zn, mb, 1);
    k_cellr<<<H, 512, 0, stream>>>(w_ihr + (long)G * H, w_hhr + (long)G * H,
                                   b_ihr + G, b_hhr + G,
                                   hnew + HB, hprev + 2 * HB, hnew + 2 * HB, cbuf + 2 * HB,
                                   nullptr, nullptr, nullptr, 0);
    if (bf) {
      k_energy<1><<<dim3(T / 64, B), 256, 0, stream>>>(kbf, hnew + 2 * HB, lens, eb, mb);
      k_pv<1><<<dim3(T / 256, B), 256, 0, stream>>>(vbf, eb, mb, lens, ctxn, Zn);
    } else {
      k_energy<0><<<dim3(T / 64, B), 256, 0, stream>>>(key, hnew + 2 * HB, lens, eb, mb);
      k_pv<0><<<dim3(T / 256, B), 256, 0, stream>>>(value, eb, mb, lens, ctxn, Zn);
    }
    k_fc1<<<MH / 4, 256, 0, stream>>>(fc1_w, fc1_b, hnew + 2 * HB, ctxn, Zn, hid);
    k_fc2<<<V, 64, 0, stream>>>(fc2_w, fc2_b, hid, out, t);
  }
}

extern "C" void kernel_launch(void* const* d_in, const int* in_sizes, int n_in,
                              void* d_out, int out_size, void* d_ws, size_t ws_size,
                              hipStream_t stream) {
  const float* key    = (const float*)d_in[0];
  const float* value  = (const float*)d_in[1];
  const int*   labels = (const int*)d_in[2];
  const int*   lens   = (const int*)d_in[3];
  const float* emb    = (const float*)d_in[4];
  const float* w_ih0  = (const float*)d_in[5];
  const float* w_hh0  = (const float*)d_in[6];
  const float* b_ih0  = (const float*)d_in[7];
  const float* b_hh0  = (const float*)d_in[8];
  const float* w_ihr  = (const float*)d_in[9];
  const float* w_hhr  = (const float*)d_in[10];
  const float* b_ihr  = (const float*)d_in[11];
  const float* b_hhr  = (const float*)d_in[12];
  const float* fc1_w  = (const float*)d_in[13];
  const float* fc1_b  = (const float*)d_in[14];
  const float* fc2_w  = (const float*)d_in[15];
  const float* fc2_b  = (const float*)d_in[16];
  float* out = (float*)d_out;
  float* ws  = (float*)d_ws;

  bool bf = ((long)ws_size >= NEED_BF);
  ushort* kbf = (ushort*)((char*)d_ws + FLOATBYTES);
  ushort* vbf = kbf + KVELEMS;

  k_init<<<(3 * HB + 255) / 256, 256, 0, stream>>>(ws);
  k_embed<<<(L * E * B + 255) / 256, 256, 0, stream>>>(labels, emb, ws + OFF_XE);
  if (bf) {
    int n4 = (int)(KVELEMS >> 2);
    k_cvt<<<4096, 256, 0, stream>>>((const float4*)key, (ushort4*)kbf, n4);
    k_cvt<<<4096, 256, 0, stream>>>((const float4*)value, (ushort4*)vbf, n4);
  }

  bool done = false;
  if (bf) {
    int perCU = 0;
    hipError_t oq = hipOccupancyMaxActiveBlocksPerMultiprocessor(
        &perCU, (const void*)k_persist, 256, 0);
    if (oq != hipSuccess) perCU = 0;
    int nb = (perCU >= 4) ? 1024 : (perCU >= 2 ? 512 : 0);
    if (nb >= 512) {
      void* args[] = {
        (void*)&kbf, (void*)&vbf, (void*)&lens,
        (void*)&w_ih0, (void*)&w_hh0, (void*)&b_ih0, (void*)&b_hh0,
        (void*)&w_ihr, (void*)&w_hhr, (void*)&b_ihr, (void*)&b_hhr,
        (void*)&fc1_w, (void*)&fc1_b, (void*)&fc2_w, (void*)&fc2_b,
        (void*)&out, (void*)&ws
      };
      hipError_t le = hipLaunchCooperativeKernel((const void*)k_persist,
                                                 dim3(nb), dim3(256), args, 0, stream);
      done = (le == hipSuccess);
    }
  }
  if (!done) {
    launch_legacy(key, value, lens, w_ih0, w_hh0, b_ih0, b_hh0,
                  w_ihr, w_hhr, b_ihr, b_hhr, fc1_w, fc1_b, fc2_w, fc2_b,
                  out, ws, kbf, vbf, bf, stream);
  }
}

// Round 3
// 16845.267 us; speedup vs baseline: 3.7937x; 3.7937x over previous
//
#include <hip/hip_runtime.h>
#include <hip/hip_bf16.h>

namespace {
constexpr int B  = 64;
constexpr int T  = 2048;
constexpr int L  = 200;
constexpr int H  = 256;
constexpr int KV = 256;
constexpr int E  = 256;
constexpr int V  = 33;
constexpr int MH = 512;
constexpr int G  = 4 * H;
constexpr int HB = H * B;       // 16384
constexpr int KVB = KV * B;     // 16384
constexpr int CS = 50;          // head chunk (steps)

// ---- legacy (round-0) float layout ----
constexpr long OFF_H   = 0;                        // h double buffer [2][3][H][B]
constexpr long OFF_C   = OFF_H  + 2L * 3 * HB;
constexpr long OFF_CTX = OFF_C  + 3L * HB;         // ctx double buffer [2][KV][B]
constexpr long OFF_Z   = OFF_CTX + 2L * KV * B;
constexpr long OFF_M   = OFF_Z  + 2L * B;
constexpr long OFF_E   = OFF_M  + B;
constexpr long OFF_HID = OFF_E  + (long)B * T;
constexpr long OFF_XE  = OFF_HID + (long)MH * B;   // xembT [L][E][B] (both paths)
constexpr long FLOATS_OLD = OFF_XE + (long)L * E * B;
constexpr long FLOATBYTES = FLOATS_OLD * 4;
constexpr long KVELEMS = (long)B * T * KV;         // 33,554,432
constexpr long NEED_BF = FLOATBYTES + 2 * KVELEMS * 2;   // legacy + bf16 KV

// ---- new-path extra region (after bf16 KV) ----
constexpr long NOFF      = NEED_BF / 4;            // float offset (16B aligned)
constexpr long NOFF_H01  = NOFF;                   // [2][2][H][B] layers 0,1 ping-pong
constexpr long NOFF_C    = NOFF_H01 + 4L * HB;     // [3][H][B]
constexpr long NOFF_H2   = NOFF_C   + 3L * HB;     // [L+1][H][B]
constexpr long NOFF_CTXA = NOFF_H2  + (long)(L + 1) * HB;   // [L+1][KV][B]
constexpr long NOFF_ZA   = NOFF_CTXA + (long)(L + 1) * KVB; // [L+1][B]
constexpr long NOFF_HIDC = NOFF_ZA  + (long)(L + 1) * B;    // [CS][MH][B]
constexpr long FLOATS_NEW = NOFF_HIDC + (long)CS * MH * B;
constexpr long NEED_NEW   = FLOATS_NEW * 4;        // ~182.1 MB
}

__device__ __forceinline__ float sigm(float x) { return 1.f / (1.f + __expf(-x)); }
__device__ __forceinline__ float tanh_f(float x) {
  float xc = fminf(fmaxf(x, -15.f), 15.f);
  float e2 = __expf(2.f * xc);
  return (e2 - 1.f) / (e2 + 1.f);
}
__device__ __forceinline__ ushort f2bf(float x) {
  unsigned u = __float_as_uint(x);
  unsigned r = (u + 0x7fffu + ((u >> 16) & 1u)) >> 16;
  return (ushort)r;
}
__device__ __forceinline__ float bf2f(unsigned v) { return __uint_as_float(v << 16); }

__device__ __forceinline__ void atomicMaxFloat(float* p, float v) {
  int old = __float_as_int(*p);
  while (__int_as_float(old) < v) {
    int assumed = old;
    old = atomicCAS((int*)p, assumed, __float_as_int(v));
    if (old == assumed) break;
  }
}

// ---------- one-time kernels ----------
__global__ void k_init(float* __restrict__ ws) {   // legacy state
  int i = blockIdx.x * blockDim.x + threadIdx.x;
  if (i < 3 * HB) { ws[OFF_H + i] = 0.f; ws[OFF_C + i] = 0.f; }
  if (i < KV * B) ws[OFF_CTX + i] = 0.f;
  if (i < B)      ws[OFF_Z + i] = 1.f;
}

__global__ void k_init2(float* __restrict__ ws) {  // new-path state
  int i = blockIdx.x * blockDim.x + threadIdx.x;
  if (i < 4 * HB)  ws[NOFF_H01 + i] = 0.f;
  if (i < 3 * HB)  ws[NOFF_C + i]   = 0.f;
  if (i < HB)      ws[NOFF_H2 + i]  = 0.f;                    // h2 slot 0
  if (i < (long)(L + 1) * KVB) ws[NOFF_CTXA + i] = 0.f;       // atomic targets
  if (i < (L + 1) * B) ws[NOFF_ZA + i] = (i < B) ? 1.f : 0.f;
}

__global__ void k_embed(const int* __restrict__ labels, const float* __restrict__ emb,
                        float* __restrict__ xembT) {
  int i = blockIdx.x * blockDim.x + threadIdx.x;
  if (i >= L * E * B) return;
  int b = i & 63, e = (i >> 6) & 255, l = i >> 14;
  int lab = labels[l * B + b];
  xembT[i] = emb[lab * E + e];
}

__global__ void k_cvt(const float4* __restrict__ src, ushort4* __restrict__ dst, int n4) {
  int i = blockIdx.x * blockDim.x + threadIdx.x;
  int stride = gridDim.x * blockDim.x;
  for (int k = i; k < n4; k += stride) {
    float4 v = src[k];
    ushort4 o;
    o.x = f2bf(v.x); o.y = f2bf(v.y); o.z = f2bf(v.z); o.w = f2bf(v.w);
    dst[k] = o;
  }
}

// ---------- LSTM cells (shared by both paths) ----------
__global__ __launch_bounds__(512) void k_cell0(
    const float* __restrict__ wih, const float* __restrict__ whh,
    const float* __restrict__ bih, const float* __restrict__ bhh,
    const float* __restrict__ xe,
    const float* __restrict__ ctx, const float* __restrict__ Z,
    const float* __restrict__ hprev,
    float* __restrict__ hnew, float* __restrict__ cst) {
  int t = threadIdx.x;
  int b = t & 63, q = (t >> 6) & 3, ks = t >> 8;
  int j = blockIdx.x;
  int row = q * H + j;
  float acc = 0.f, s0 = 0.f, s1 = 0.f, s2 = 0.f, s3 = 0.f, a2 = 0.f;
  if (ks == 0) {
    acc = bih[row] + bhh[row];
    const float* wi = wih + (long)row * (E + KV);
    #pragma unroll 4
    for (int k = 0; k < E; k += 4) {
      s0 += wi[k]   * xe[(k)   * B + b];
      s1 += wi[k+1] * xe[(k+1) * B + b];
      s2 += wi[k+2] * xe[(k+2) * B + b];
      s3 += wi[k+3] * xe[(k+3) * B + b];
    }
    const float* wh = whh + (long)row * H;
    #pragma unroll 4
    for (int k = 0; k < 128; k += 2) {
      a2 += wh[k]   * hprev[(k)   * B + b];
      a2 += wh[k+1] * hprev[(k+1) * B + b];
    }
    acc += (s0 + s1) + (s2 + s3) + a2;
  } else {
    float zz = 1.f / fmaxf(Z[b], 1e-12f);
    const float* wi = wih + (long)row * (E + KV) + E;
    #pragma unroll 4
    for (int k = 0; k < KV; k += 4) {
      s0 += wi[k]   * ctx[(k)   * B + b];
      s1 += wi[k+1] * ctx[(k+1) * B + b];
      s2 += wi[k+2] * ctx[(k+2) * B + b];
      s3 += wi[k+3] * ctx[(k+3) * B + b];
    }
    const float* wh = whh + (long)row * H + 128;
    #pragma unroll 4
    for (int k = 0; k < 128; k += 2) {
      a2 += wh[k]   * hprev[(128 + k)     * B + b];
      a2 += wh[k+1] * hprev[(128 + k + 1) * B + b];
    }
    acc = ((s0 + s1) + (s2 + s3)) * zz + a2;
  }
  __shared__ float sh[2][4][64];
  sh[ks][q][b] = acc;
  __syncthreads();
  if (t < 64) {
    int bb = t;
    float gi = sh[0][0][bb] + sh[1][0][bb];
    float gf = sh[0][1][bb] + sh[1][1][bb];
    float gg = sh[0][2][bb] + sh[1][2][bb];
    float go = sh[0][3][bb] + sh[1][3][bb];
    float c = sigm(gf) * cst[j * B + bb] + sigm(gi) * tanh_f(gg);
    float h = sigm(go) * tanh_f(c);
    cst[j * B + bb] = c;
    hnew[j * B + bb] = h;
  }
}

__global__ __launch_bounds__(512) void k_cellr(
    const float* __restrict__ wih, const float* __restrict__ whh,
    const float* __restrict__ bih, const float* __restrict__ bhh,
    const float* __restrict__ hin, const float* __restrict__ hprevL,
    float* __restrict__ hnewL, float* __restrict__ cst,
    float* __restrict__ ctxn, float* __restrict__ Zn, float* __restrict__ m, int aux) {
  int t = threadIdx.x;
  int b = t & 63, q = (t >> 6) & 3, ks = t >> 8;
  int j = blockIdx.x;
  int row = q * H + j;
  if (aux) {
    int gid = blockIdx.x * 512 + t;
    if (gid < KV * B) ctxn[gid] = 0.f;
    if (gid < B) { Zn[gid] = 0.f; m[gid] = -3.4e38f; }
  }
  float acc = ks ? 0.f : (bih[row] + bhh[row]);
  float a1 = 0.f, a2 = 0.f, a3 = 0.f, a4 = 0.f;
  const float* wi = wih + (long)row * H + ks * 128;
  const float* wh = whh + (long)row * H + ks * 128;
  int k0 = ks * 128;
  #pragma unroll 4
  for (int k = 0; k < 128; k += 2) {
    a1 += wi[k]   * hin[(k0 + k)     * B + b];
    a2 += wi[k+1] * hin[(k0 + k + 1) * B + b];
    a3 += wh[k]   * hprevL[(k0 + k)     * B + b];
    a4 += wh[k+1] * hprevL[(k0 + k + 1) * B + b];
  }
  acc += (a1 + a2) + (a3 + a4);
  __shared__ float sh[2][4][64];
  sh[ks][q][b] = acc;
  __syncthreads();
  if (t < 64) {
    int bb = t;
    float gi = sh[0][0][bb] + sh[1][0][bb];
    float gf = sh[0][1][bb] + sh[1][1][bb];
    float gg = sh[0][2][bb] + sh[1][2][bb];
    float go = sh[0][3][bb] + sh[1][3][bb];
    float c = sigm(gf) * cst[j * B + bb] + sigm(gi) * tanh_f(gg);
    float h = sigm(go) * tanh_f(c);
    cst[j * B + bb] = c;
    hnewL[j * B + bb] = h;
  }
}

// ---------- fused single-pass attention (new path) ----------
// grid (T/256, B), block 256 = 4 waves x 64 rows; exp clamped, no max pass
__global__ __launch_bounds__(256) void k_attn(
    const ushort* __restrict__ kbf, const ushort* __restrict__ vbf,
    const float* __restrict__ h2, const int* __restrict__ lens,
    float* __restrict__ ctxn, float* __restrict__ Zn) {
  int b = blockIdx.y;
  int len = lens[b];
  int r0 = blockIdx.x * 256;
  if (r0 >= len) return;
  int tid = threadIdx.x;
  int wave = tid >> 6, lane = tid & 63;
  float q0 = h2[(4 * lane + 0) * B + b];
  float q1 = h2[(4 * lane + 1) * B + b];
  float q2 = h2[(4 * lane + 2) * B + b];
  float q3 = h2[(4 * lane + 3) * B + b];
  float a0 = 0.f, a1 = 0.f, a2 = 0.f, a3 = 0.f, zp = 0.f;
  int rs = r0 + wave * 64;
  int re = min(rs + 64, len);
  for (int r = rs; r < re; ++r) {
    size_t off = ((size_t)(b * T + r)) * KV + 4 * lane;
    uint2 kd = *(const uint2*)(kbf + off);
    uint2 vd = *(const uint2*)(vbf + off);
    float e = bf2f(kd.x & 0xffffu) * q0
            + __uint_as_float(kd.x & 0xffff0000u) * q1
            + bf2f(kd.y & 0xffffu) * q2
            + __uint_as_float(kd.y & 0xffff0000u) * q3;
    #pragma unroll
    for (int o = 32; o; o >>= 1) e += __shfl_xor(e, o, 64);
    float w = __expf(fminf(e, 50.f));
    a0 += w * bf2f(vd.x & 0xffffu);
    a1 += w * __uint_as_float(vd.x & 0xffff0000u);
    a2 += w * bf2f(vd.y & 0xffffu);
    a3 += w * __uint_as_float(vd.y & 0xffff0000u);
    zp += w;
  }
  __shared__ float sh[4][256];
  __shared__ float shz[4];
  sh[wave][4 * lane + 0] = a0;
  sh[wave][4 * lane + 1] = a1;
  sh[wave][4 * lane + 2] = a2;
  sh[wave][4 * lane + 3] = a3;
  if (lane == 0) shz[wave] = zp;
  __syncthreads();
  float s = sh[0][tid] + sh[1][tid] + sh[2][tid] + sh[3][tid];
  atomicAdd(&ctxn[tid * B + b], s);
  if (tid == 0) atomicAdd(&Zn[b], shz[0] + shz[1] + shz[2] + shz[3]);
}

// ---------- deferred MLP head (new path) ----------
__global__ __launch_bounds__(256) void k_fc1c(
    const float* __restrict__ w, const float* __restrict__ bias,
    const float* __restrict__ h2a, const float* __restrict__ ctxa,
    const float* __restrict__ za, float* __restrict__ hidc, int t0) {
  int s = blockIdx.y;
  int t = t0 + s;
  const float* h2  = h2a  + (long)(t + 1) * HB;
  const float* ctx = ctxa + (long)(t + 1) * KVB;
  int tid = threadIdx.x;
  int b = tid & 63, jl = tid >> 6;
  int j = blockIdx.x * 4 + jl;
  float zz = 1.f / fmaxf(za[(t + 1) * B + b], 1e-12f);
  const float* wr = w + (long)j * (H + KV);
  float s0 = 0.f, s1 = 0.f, c0 = 0.f, c1 = 0.f;
  #pragma unroll 4
  for (int k = 0; k < 256; k += 2) {
    s0 += wr[k]       * h2[(k)   * B + b];
    s1 += wr[k+1]     * h2[(k+1) * B + b];
    c0 += wr[256 + k]   * ctx[(k)   * B + b];
    c1 += wr[256 + k+1] * ctx[(k+1) * B + b];
  }
  float acc = bias[j] + (s0 + s1) + (c0 + c1) * zz;
  hidc[((long)s * MH + j) * B + b] = fmaxf(acc, 0.f);
}

__global__ __launch_bounds__(64) void k_fc2c(
    const float* __restrict__ w, const float* __restrict__ bias,
    const float* __restrict__ hidc, float* __restrict__ out, int t0) {
  int s = blockIdx.y;
  int v = blockIdx.x;
  int b = threadIdx.x;
  const float* hid = hidc + (long)s * MH * B;
  const float* wr = w + (long)v * MH;
  float s0 = 0.f, s1 = 0.f, s2 = 0.f, s3 = 0.f;
  #pragma unroll 4
  for (int k = 0; k < MH; k += 4) {
    s0 += wr[k]   * hid[(k)   * B + b];
    s1 += wr[k+1] * hid[(k+1) * B + b];
    s2 += wr[k+2] * hid[(k+2) * B + b];
    s3 += wr[k+3] * hid[(k+3) * B + b];
  }
  out[((long)b * L + (t0 + s)) * V + v] = bias[v] + (s0 + s1) + (s2 + s3);
}

// ---------- legacy fallback extras ----------
template <int BF>
__global__ __launch_bounds__(256) void k_energy(
    const void* __restrict__ keyp, const float* __restrict__ h2,
    const int* __restrict__ lens, float* __restrict__ e, float* __restrict__ m) {
  int b = blockIdx.y;
  int len = lens[b];
  int wave = threadIdx.x >> 6, lane = threadIdx.x & 63;
  int t0 = (blockIdx.x * 4 + wave) * 16;
  if (t0 >= len) return;
  float h0 = h2[(4 * lane + 0) * B + b];
  float h1 = h2[(4 * lane + 1) * B + b];
  float h2v = h2[(4 * lane + 2) * B + b];
  float h3 = h2[(4 * lane + 3) * B + b];
  int tend = min(t0 + 16, len);
  float wmax = -3.4e38f;
  for (int t = t0; t < tend; t++) {
    float4 kv;
    if (BF) {
      const uint2* p = (const uint2*)((const ushort*)keyp + (size_t)(b * T + t) * KV + 4 * lane);
      uint2 d = *p;
      kv.x = bf2f(d.x & 0xffffu);
      kv.y = __uint_as_float(d.x & 0xffff0000u);
      kv.z = bf2f(d.y & 0xffffu);
      kv.w = __uint_as_float(d.y & 0xffff0000u);
    } else {
      kv = ((const float4*)((const float*)keyp + (size_t)(b * T + t) * KV))[lane];
    }
    float s = kv.x * h0 + kv.y * h1 + kv.z * h2v + kv.w * h3;
    #pragma unroll
    for (int off = 32; off; off >>= 1) s += __shfl_xor(s, off, 64);
    if (lane == 0) e[b * T + t] = s;
    wmax = fmaxf(wmax, s);
  }
  if (lane == 0) atomicMaxFloat(&m[b], wmax);
}

template <int BF>
__global__ __launch_bounds__(256) void k_pv(
    const void* __restrict__ valp, const float* __restrict__ e, const float* __restrict__ m,
    const int* __restrict__ lens, float* __restrict__ ctxn, float* __restrict__ Zn) {
  int b = blockIdx.y;
  int len = lens[b];
  int t0blk = blockIdx.x * 256;
  if (t0blk >= len) return;
  int wave = threadIdx.x >> 6, lane = threadIdx.x & 63;
  float mb = m[b];
  float a0 = 0.f, a1 = 0.f, a2 = 0.f, a3 = 0.f, zp = 0.f;
  int t0 = t0blk + wave * 64;
  int tend = min(t0 + 64, len);
  for (int t = t0; t < tend; t++) {
    float w = __expf(e[b * T + t] - mb);
    float4 vv;
    if (BF) {
      const uint2* p = (const uint2*)((const ushort*)valp + (size_t)(b * T + t) * KV + 4 * lane);
      uint2 d = *p;
      vv.x = bf2f(d.x & 0xffffu);
      vv.y = __uint_as_float(d.x & 0xffff0000u);
      vv.z = bf2f(d.y & 0xffffu);
      vv.w = __uint_as_float(d.y & 0xffff0000u);
    } else {
      vv = ((const float4*)((const float*)valp + (size_t)(b * T + t) * KV))[lane];
    }
    a0 += w * vv.x; a1 += w * vv.y; a2 += w * vv.z; a3 += w * vv.w;
    zp += w;
  }
  __shared__ float sh[4][256];
  __shared__ float shz[4];
  sh[wave][4 * lane + 0] = a0;
  sh[wave][4 * lane + 1] = a1;
  sh[wave][4 * lane + 2] = a2;
  sh[wave][4 * lane + 3] = a3;
  if (lane == 0) shz[wave] = zp;
  __syncthreads();
  if (wave == 0) {
    #pragma unroll
    for (int r = 0; r < 4; r++) {
      int d = lane * 4 + r;
      float s = sh[0][d] + sh[1][d] + sh[2][d] + sh[3][d];
      atomicAdd(&ctxn[d * B + b], s);
    }
    if (lane == 0) atomicAdd(&Zn[b], shz[0] + shz[1] + shz[2] + shz[3]);
  }
}

__global__ __launch_bounds__(256) void k_fc1(
    const float* __restrict__ w, const float* __restrict__ bias,
    const float* __restrict__ h2, const float* __restrict__ ctxn, const float* __restrict__ Zn,
    float* __restrict__ hid) {
  int t = threadIdx.x;
  int b = t & 63, jl = t >> 6;
  int j = blockIdx.x * 4 + jl;
  float zz = 1.f / fmaxf(Zn[b], 1e-12f);
  const float* wr = w + (long)j * (H + KV);
  float s0 = 0.f, s1 = 0.f, s2 = 0.f, s3 = 0.f, a2 = 0.f, a3 = 0.f;
  #pragma unroll 4
  for (int k = 0; k < H; k += 4) {
    s0 += wr[k]   * h2[(k)   * B + b];
    s1 += wr[k+1] * h2[(k+1) * B + b];
    s2 += wr[k+2] * h2[(k+2) * B + b];
    s3 += wr[k+3] * h2[(k+3) * B + b];
  }
  #pragma unroll 4
  for (int k = 0; k < KV; k += 2) {
    a2 += wr[H + k]     * ctxn[(k)   * B + b];
    a3 += wr[H + k + 1] * ctxn[(k+1) * B + b];
  }
  float acc = bias[j] + (s0 + s1) + (s2 + s3) + (a2 + a3) * zz;
  hid[j * B + b] = fmaxf(acc, 0.f);
}

__global__ __launch_bounds__(64) void k_fc2(
    const float* __restrict__ w, const float* __restrict__ bias,
    const float* __restrict__ hid, float* __restrict__ out, int step) {
  int b = threadIdx.x;
  int v = blockIdx.x;
  const float* wr = w + (long)v * MH;
  float s0 = 0.f, s1 = 0.f, s2 = 0.f, s3 = 0.f;
  #pragma unroll 4
  for (int k = 0; k < MH; k += 4) {
    s0 += wr[k]   * hid[(k)   * B + b];
    s1 += wr[k+1] * hid[(k+1) * B + b];
    s2 += wr[k+2] * hid[(k+2) * B + b];
    s3 += wr[k+3] * hid[(k+3) * B + b];
  }
  out[((long)b * L + step) * V + v] = bias[v] + (s0 + s1) + (s2 + s3);
}

static void launch_legacy(const float* key, const float* value, const int* lens,
                          const float* w_ih0, const float* w_hh0,
                          const float* b_ih0, const float* b_hh0,
                          const float* w_ihr, const float* w_hhr,
                          const float* b_ihr, const float* b_hhr,
                          const float* fc1_w, const float* fc1_b,
                          const float* fc2_w, const float* fc2_b,
                          float* out, float* ws,
                          const ushort* kbf, const ushort* vbf, bool bf,
                          hipStream_t stream) {
  float* hbuf = ws + OFF_H;
  float* cbuf = ws + OFF_C;
  float* ctxb = ws + OFF_CTX;
  float* Zb   = ws + OFF_Z;
  float* mb   = ws + OFF_M;
  float* eb   = ws + OFF_E;
  float* hid  = ws + OFF_HID;
  float* xe   = ws + OFF_XE;
  for (int t = 0; t < L; t++) {
    int cur = t & 1, nxt = cur ^ 1;
    float* hprev = hbuf + (long)cur * 3 * HB;
    float* hnew  = hbuf + (long)nxt * 3 * HB;
    float* ctxc  = ctxb + (long)cur * KV * B;
    float* ctxn  = ctxb + (long)nxt * KV * B;
    float* Zc = Zb + cur * B;
    float* Zn = Zb + nxt * B;

    k_cell0<<<H, 512, 0, stream>>>(w_ih0, w_hh0, b_ih0, b_hh0,
                                   xe + (long)t * E * B, ctxc, Zc,
                                   hprev, hnew, cbuf);
    k_cellr<<<H, 512, 0, stream>>>(w_ihr, w_hhr, b_ihr, b_hhr,
                                   hnew, hprev + HB, hnew + HB, cbuf + HB,
                                   ctxn, Zn, mb, 1);
    k_cellr<<<H, 512, 0, stream>>>(w_ihr + (long)G * H, w_hhr + (long)G * H,
                                   b_ihr + G, b_hhr + G,
                                   hnew + HB, hprev + 2 * HB, hnew + 2 * HB, cbuf + 2 * HB,
                                   nullptr, nullptr, nullptr, 0);
    if (bf) {
      k_energy<1><<<dim3(T / 64, B), 256, 0, stream>>>(kbf, hnew + 2 * HB, lens, eb, mb);
      k_pv<1><<<dim3(T / 256, B), 256, 0, stream>>>(vbf, eb, mb, lens, ctxn, Zn);
    } else {
      k_energy<0><<<dim3(T / 64, B), 256, 0, stream>>>(key, hnew + 2 * HB, lens, eb, mb);
      k_pv<0><<<dim3(T / 256, B), 256, 0, stream>>>(value, eb, mb, lens, ctxn, Zn);
    }
    k_fc1<<<MH / 4, 256, 0, stream>>>(fc1_w, fc1_b, hnew + 2 * HB, ctxn, Zn, hid);
    k_fc2<<<V, 64, 0, stream>>>(fc2_w, fc2_b, hid, out, t);
  }
}

extern "C" void kernel_launch(void* const* d_in, const int* in_sizes, int n_in,
                              void* d_out, int out_size, void* d_ws, size_t ws_size,
                              hipStream_t stream) {
  const float* key    = (const float*)d_in[0];
  const float* value  = (const float*)d_in[1];
  const int*   labels = (const int*)d_in[2];
  const int*   lens   = (const int*)d_in[3];
  const float* emb    = (const float*)d_in[4];
  const float* w_ih0  = (const float*)d_in[5];
  const float* w_hh0  = (const float*)d_in[6];
  const float* b_ih0  = (const float*)d_in[7];
  const float* b_hh0  = (const float*)d_in[8];
  const float* w_ihr  = (const float*)d_in[9];
  const float* w_hhr  = (const float*)d_in[10];
  const float* b_ihr  = (const float*)d_in[11];
  const float* b_hhr  = (const float*)d_in[12];
  const float* fc1_w  = (const float*)d_in[13];
  const float* fc1_b  = (const float*)d_in[14];
  const float* fc2_w  = (const float*)d_in[15];
  const float* fc2_b  = (const float*)d_in[16];
  float* out = (float*)d_out;
  float* ws  = (float*)d_ws;

  bool bf      = ((long)ws_size >= NEED_BF);
  bool newpath = ((long)ws_size >= NEED_NEW);
  ushort* kbf = (ushort*)((char*)d_ws + FLOATBYTES);
  ushort* vbf = kbf + KVELEMS;

  k_embed<<<(L * E * B + 255) / 256, 256, 0, stream>>>(labels, emb, ws + OFF_XE);
  if (bf) {
    int n4 = (int)(KVELEMS >> 2);
    k_cvt<<<4096, 256, 0, stream>>>((const float4*)key, (ushort4*)kbf, n4);
    k_cvt<<<4096, 256, 0, stream>>>((const float4*)value, (ushort4*)vbf, n4);
  }

  if (newpath) {
    k_init2<<<(int)(((long)(L + 1) * KVB + 255) / 256), 256, 0, stream>>>(ws);
    float* h01  = ws + NOFF_H01;
    float* cst  = ws + NOFF_C;
    float* h2a  = ws + NOFF_H2;
    float* ctxa = ws + NOFF_CTXA;
    float* za   = ws + NOFF_ZA;
    float* hidc = ws + NOFF_HIDC;
    float* xe   = ws + OFF_XE;

    for (int t = 0; t < L; t++) {
      int cur = t & 1, nxt = cur ^ 1;
      float* h0c = h01 + (long)cur * 2 * HB;
      float* h0n = h01 + (long)nxt * 2 * HB;
      k_cell0<<<H, 512, 0, stream>>>(w_ih0, w_hh0, b_ih0, b_hh0,
                                     xe + (long)t * E * B,
                                     ctxa + (long)t * KVB, za + (long)t * B,
                                     h0c, h0n, cst);
      k_cellr<<<H, 512, 0, stream>>>(w_ihr, w_hhr, b_ihr, b_hhr,
                                     h0n, h0c + HB, h0n + HB, cst + HB,
                                     nullptr, nullptr, nullptr, 0);
      k_cellr<<<H, 512, 0, stream>>>(w_ihr + (long)G * H, w_hhr + (long)G * H,
                                     b_ihr + G, b_hhr + G,
                                     h0n + HB, h2a + (long)t * HB, h2a + (long)(t + 1) * HB,
                                     cst + 2 * HB, nullptr, nullptr, nullptr, 0);
      k_attn<<<dim3(T / 256, B), 256, 0, stream>>>(kbf, vbf, h2a + (long)(t + 1) * HB,
                                                   lens, ctxa + (long)(t + 1) * KVB,
                                                   za + (long)(t + 1) * B);
    }
    for (int c = 0; c < L / CS; c++) {
      int t0 = c * CS;
      k_fc1c<<<dim3(MH / 4, CS), 256, 0, stream>>>(fc1_w, fc1_b, h2a, ctxa, za, hidc, t0);
      k_fc2c<<<dim3(V, CS), 64, 0, stream>>>(fc2_w, fc2_b, hidc, out, t0);
    }
  } else {
    k_init<<<(3 * HB + 255) / 256, 256, 0, stream>>>(ws);
    launch_legacy(key, value, lens, w_ih0, w_hh0, b_ih0, b_hh0,
                  w_ihr, w_hhr, b_ihr, b_hhr, fc1_w, fc1_b, fc2_w, fc2_b,
                  out, ws, kbf, vbf, bf, stream);
  }
}